// Round 5
// baseline (275.691 us; speedup 1.0000x reference)
//
#include <hip/hip_runtime.h>
#include <hip/hip_bf16.h>
#include <cstdint>

typedef __bf16 bf16_t;
typedef __bf16 bf16x8 __attribute__((ext_vector_type(8)));
typedef float  floatx4 __attribute__((ext_vector_type(4)));

typedef const __attribute__((address_space(1))) unsigned int* gptr_t;
typedef __attribute__((address_space(3))) unsigned int* lptr_t;
typedef __attribute__((address_space(3))) const char* l3p;

static __device__ __forceinline__ void gl2lds16(const bf16_t* g, bf16_t* l) {
  __builtin_amdgcn_global_load_lds((gptr_t)g, (lptr_t)l, 16, 0, 0);
}

#define BAR()     asm volatile("s_barrier" ::: "memory")
#define VMW(NSTR) asm volatile("s_waitcnt vmcnt(" NSTR ")" ::: "memory")
#define LGKM0()   asm volatile("s_waitcnt lgkmcnt(0)" ::: "memory")
#define SB()      __builtin_amdgcn_sched_barrier(0)

// opaque LDS read: waitcnt pass inserts NO vmcnt before it and tracks no lgkm
// for it -> all read-vs-DMA ordering is ours (VMW/LGKM0 protocol below).
#define DSR(D, P, OFS) \
  asm volatile("ds_read_b128 %0, %1 offset:%2" : "=v"(D) : "v"(P), "i"(OFS))

// 16-MFMA cluster (one A-half x one K-half x all 4 j): acc[F..F+3][0..3].
static __device__ __forceinline__ void mm16h(floatx4 (&acc)[8][4], int F,
                                             const bf16x8 (&aa)[4],
                                             const bf16x8 (&bb)[4]) {
  __builtin_amdgcn_s_setprio(1);
#pragma unroll
  for (int f = 0; f < 4; ++f)
#pragma unroll
    for (int j = 0; j < 4; ++j)
      acc[F + f][j] = __builtin_amdgcn_mfma_f32_16x16x32_bf16(
          aa[f], bb[j], acc[F + f][j], 0, 0, 0);
  __builtin_amdgcn_s_setprio(0);
}

// ---------------------------------------------------------------------------
// ROUND-14: 256x256 8-phase GEMM, DS-BALANCED phase split.
// R13 post-mortem arithmetic: per K-tile per CU, LDS traffic = A 32KB x4
// waves + B 32KB x2 = 192 ds_read_b128 x ~12cy = 2304 cy vs MFMA 2484 cy --
// balanced in total, but the C-quadrant split issued 12/8/4/0 reads/phase:
// ph0's 96-read burst = 1152 cy DS vs 621 cy MFMA, exposed serially by the
// same-phase lgkmcnt(0). Fix: phase = (A-half x K-half), reads 8/4/8/4:
//   ph0: rd a03.kh0(4)+b.kh0(4); STG other.Ak0+Ak1; BAR;lgkm0; A03xB.kh0; BAR
//   ph1: rd a47.kh0(4);          STG other.Bk0+Bk1; BAR;lgkm0; A47xB.kh0; BAR
//   ph2: rd a03.kh1(4)+b.kh1(4);                    BAR;lgkm0; A03xB.kh1; BAR
//   ph3: rd a47.kh1(4);                             BAR;lgkm0; A47xB.kh1;
//                                                   VMW(0);BAR
// Max DS burst/phase = 64 reads = 768 cy ~ MFMA 621 cy.
// Waits: per-phase lgkmcnt(0) (covers only this wave's just-issued asm reads)
// + sched_barrier(0) fences (rule #18). One VMW(0) per tile at ph3-end:
// stages were issued ph0/ph1 (>=2 phases ~ 1500cy >= 900cy HBM latency) ->
// free in steady state; confirms buf(t+1) complete before ph0(t+1) reads.
// Overwrite safety: STG(buf t+1 = buf t-1) issues at ph0(t), after
// BAR(end t-1); all t-1 reads completed before each wave's last MFMA(t-1)
// (per-phase lgkm0) which precede that BAR. Checked.
// Geometry: 8 waves (2Mx4N), per-wave 128x64 (acc[8][4]), BK=64 as two K=32
// halves in separate arrays, XOR chunk swizzle, panel-walking XCD swizzle.
// ---------------------------------------------------------------------------
template<int HAS_BIAS, int EXP_COLSUM, int SPLIT3>
__global__ __launch_bounds__(512, 2)
void gemm256(const bf16_t* __restrict__ A, const bf16_t* __restrict__ Bt,
             void* __restrict__ Cv,
             const float* __restrict__ b0v, const float* __restrict__ b1v,
             const float* __restrict__ b2v,
             float* __restrict__ L,
             int M, int N, int K, int ldC, float alpha,
             long sA, long sB, long sC,
             long co0, long co1, long co2,
             int mbShift, int ldTv, long sTv)
{
  __shared__ __align__(16) bf16_t sA0k0[8192];
  __shared__ __align__(16) bf16_t sA0k1[8192];
  __shared__ __align__(16) bf16_t sB0k0[8192];
  __shared__ __align__(16) bf16_t sB0k1[8192];
  __shared__ __align__(16) bf16_t sA1k0[8192];
  __shared__ __align__(16) bf16_t sA1k1[8192];
  __shared__ __align__(16) bf16_t sB1k0[8192];
  __shared__ __align__(16) bf16_t sB1k1[8192];

  const int bz = blockIdx.z;
  A  += bz * sA;
  Bt += bz * sB;

  // XCD-aware swizzle v2 (panel-walking)
  int bx = blockIdx.x, by = blockIdx.y;
  {
    const int gx = gridDim.x, gy = gridDim.y;
    const int nb = gx * gy;
    if (((nb & 7) == 0) && ((gx & 3) == 0) && ((gy & 7) == 0)) {
      const int id   = bx + gx * by;
      const int xcd  = id & 7;
      const int o    = id >> 3;
      const int rows = gy >> 3;
      const int pw   = rows << 2;
      const int p    = o / pw;
      const int r    = o - p * pw;
      by = xcd * rows + (r >> 2);
      bx = (p << 2) + (r & 3);
    }
  }

  const int gn0 = bx * 256;
  const int m0  = by * 256;
  const int tid  = threadIdx.x;
  const int lane = tid & 63;
  const int wave = tid >> 6;
  const int wm   = wave >> 2;      // 0..1  (M half)
  const int wn   = wave & 3;       // 0..3  (N quarter)
  const int lm   = lane & 15;
  const int quad = lane >> 4;

  int n0 = gn0, which = 0;
  bf16_t* Cb = (bf16_t*)Cv;
  const float* bias = b0v;
  if (SPLIT3) {
    which = gn0 >> 10;
    n0 = gn0 & 1023;
    Cb += (which == 0) ? co0 : (which == 1) ? co1 : co2;
    bias = (which == 0) ? b0v : (which == 1) ? b1v : b2v;
  }

  // staging: thread tid -> row tid>>2 (+128 for 2nd load), LDS chunk tid&3;
  // global chunk pre-swizzled with row bits 1-2 (involution).
  const int srow = tid >> 2;
  const int scol = ((tid ^ (tid >> 3)) & 3) * 8;
  const bf16_t* pA = A  + (long)(m0  + srow) * K + scol;
  const bf16_t* pB = Bt + (long)(gn0 + srow) * K + scol;

  const int nt = K >> 6;            // K-tiles of 64 (even, >= 4)

  // fragment-read base byte offsets (chunk XOR matches staging involution)
  const int csz  = ((quad ^ (lm >> 1)) & 3) * 16;
  const int arow = (wm * 128 + lm) * 64 + csz;
  const int brow = (wn * 64  + lm) * 64 + csz;

#define STG(DST, GP) do { \
    gl2lds16((GP), &DST[tid * 8]); \
    gl2lds16((GP) + (long)128 * K, &DST[tid * 8 + 4096]); } while (0)

#define RDA(DSTR, ARR, O0) do { \
    l3p _p = (l3p)(ARR) + arow; \
    DSR(DSTR[0], _p, (O0) + 0);    DSR(DSTR[1], _p, (O0) + 1024); \
    DSR(DSTR[2], _p, (O0) + 2048); DSR(DSTR[3], _p, (O0) + 3072); } while (0)

#define RDB(DSTR, ARR) do { \
    l3p _p = (l3p)(ARR) + brow; \
    DSR(DSTR[0], _p, 0);    DSR(DSTR[1], _p, 1024); \
    DSR(DSTR[2], _p, 2048); DSR(DSTR[3], _p, 3072); } while (0)

  // One K-tile = 4 phases (reads 8/4/8/4), buf(t+1) staged ph0/ph1.
#define TILEX(AK0, AK1, BK0, BK1, OAK0, OAK1, OBK0, OBK1, T, ST, DO_W) do { \
    /* ph0: A03 x B, kh0 */ \
    RDA(a, AK0, 0); RDB(b, BK0); \
    if (ST) { STG(OAK0, pA + ((T) + 1) * 64); \
              STG(OAK1, pA + ((T) + 1) * 64 + 32); } \
    SB(); BAR(); LGKM0(); SB(); \
    mm16h(acc, 0, a, b); \
    SB(); BAR(); \
    /* ph1: A47 x B, kh0 */ \
    RDA(a2, AK0, 4096); \
    if (ST) { STG(OBK0, pB + ((T) + 1) * 64); \
              STG(OBK1, pB + ((T) + 1) * 64 + 32); } \
    SB(); BAR(); LGKM0(); SB(); \
    mm16h(acc, 4, a2, b); \
    SB(); BAR(); \
    /* ph2: A03 x B, kh1 */ \
    RDA(a, AK1, 0); RDB(b2, BK1); \
    SB(); BAR(); LGKM0(); SB(); \
    mm16h(acc, 0, a, b2); \
    SB(); BAR(); \
    /* ph3: A47 x B, kh1; confirm buf(t+1) staged */ \
    RDA(a2, AK1, 4096); \
    SB(); BAR(); LGKM0(); SB(); \
    mm16h(acc, 4, a2, b2); \
    SB(); if (DO_W) VMW("0"); BAR(); \
  } while (0)

  floatx4 acc[8][4];
#pragma unroll
  for (int f = 0; f < 8; ++f)
#pragma unroll
    for (int j = 0; j < 4; ++j)
      acc[f][j] = (floatx4)(0.f);

  bf16x8 a[4], a2[4], b[4], b2[4];

  // prologue: stage tile0's 4 halves, full drain, barrier.
  STG(sA0k0, pA);
  STG(sA0k1, pA + 32);
  STG(sB0k0, pB);
  STG(sB0k1, pB + 32);
  VMW("0"); BAR();

  const int npair = nt >> 1;
  for (int p = 0; p < npair - 1; ++p) {
    const int t0 = 2 * p;
    TILEX(sA0k0, sA0k1, sB0k0, sB0k1, sA1k0, sA1k1, sB1k0, sB1k1, t0,     1, 1);
    TILEX(sA1k0, sA1k1, sB1k0, sB1k1, sA0k0, sA0k1, sB0k0, sB0k1, t0 + 1, 1, 1);
  }
  TILEX(sA0k0, sA0k1, sB0k0, sB0k1, sA1k0, sA1k1, sB1k0, sB1k1, nt - 2, 1, 1);
  TILEX(sA1k0, sA1k1, sB1k0, sB1k1, sA0k0, sA0k1, sB0k0, sB0k1, nt - 1, 0, 0);

  // ---------------- epilogue (C/D layout: col=lm, row=quad*4+r) ------------
  __syncthreads();
  const int r8 = lane >> 3;
  const int c8 = lane & 7;

  if (SPLIT3 && which == 2) {
    // transposed store: Vt[b][d][s]; per-wave scratch [16][144] = 2304 elems
    bf16_t* myT = (wave < 3) ? (sA0k0 + wave * 2304)
                : (wave < 6) ? (sA0k1 + (wave - 3) * 2304)
                             : (sB0k0 + (wave - 6) * 2304);
    const int b_  = m0 >> mbShift;
    const int s0 = m0 & ((1 << mbShift) - 1);
#pragma unroll
    for (int j = 0; j < 4; ++j) {
      const float bv = HAS_BIAS ? bias[n0 + wn * 64 + j * 16 + lm] : 0.f;
#pragma unroll
      for (int f = 0; f < 8; ++f)
#pragma unroll
        for (int r = 0; r < 4; ++r)
          myT[lm * 144 + f * 16 + quad * 4 + r] = (bf16_t)(acc[f][j][r] + bv);
      // per-wave region + in-order DS pipe: no barrier needed
#pragma unroll
      for (int t2 = 0; t2 < 4; ++t2) {
        const int dr = (t2 & 1) * 8 + r8;
        const int ck = (t2 >> 1) * 8 + c8;
        const bf16x8 vv = *(const bf16x8*)&myT[dr * 144 + ck * 8];
        *(bf16x8*)&Cb[(long)b_ * sTv + (long)(n0 + wn * 64 + j * 16 + dr) * ldTv
                      + s0 + wm * 128 + ck * 8] = vv;
      }
    }
  } else {
    // per-wave scratch [16][68] = 1088 elems
    bf16_t* myEp = (wave < 7) ? (sA0k0 + wave * 1088) : sA0k1;
    float csum[4] = {0.f, 0.f, 0.f, 0.f};
    float bv[4];
#pragma unroll
    for (int j = 0; j < 4; ++j)
      bv[j] = HAS_BIAS ? bias[n0 + wn * 64 + j * 16 + lm] : 0.f;
#pragma unroll
    for (int f = 0; f < 8; ++f) {
#pragma unroll
      for (int j = 0; j < 4; ++j)
#pragma unroll
        for (int r = 0; r < 4; ++r) {
          float v = acc[f][j][r];
          if (EXP_COLSUM) { v = __expf(alpha * v); csum[j] += v; }
          v += bv[j];
          myEp[(quad * 4 + r) * 68 + j * 16 + lm] = (bf16_t)v;
        }
#pragma unroll
      for (int t2 = 0; t2 < 2; ++t2) {
        const int row = t2 * 8 + r8;
        const bf16x8 vv = *(const bf16x8*)&myEp[row * 68 + c8 * 8];
        *(bf16x8*)&Cb[bz * sC + (long)(m0 + wm * 128 + f * 16 + row) * ldC
                      + n0 + wn * 64 + c8 * 8] = vv;
      }
    }
    if (EXP_COLSUM) {
#pragma unroll
      for (int j = 0; j < 4; ++j) {
        float v = csum[j];
        v += __shfl_xor(v, 16);
        v += __shfl_xor(v, 32);
        if (quad == 0)
          atomicAdd(&L[bz * N + gn0 + wn * 64 + j * 16 + lm], v);
      }
    }
  }
#undef STG
#undef RDA
#undef RDB
#undef TILEX
}

// ---------------------------------------------------------------------------
// Round-9 128x128 kernel (ctx / out GEMMs: 512 blocks each keeps machine full)
// ---------------------------------------------------------------------------
template<int OUT_BF16, int HAS_BIAS, int EXP_COLSUM, int SPLIT3>
__global__ __launch_bounds__(256, 4)
void gemm_nt(const bf16_t* __restrict__ A, const bf16_t* __restrict__ Bt,
             void* __restrict__ Cv,
             const float* __restrict__ b0, const float* __restrict__ b1,
             const float* __restrict__ b2,
             float* __restrict__ L,
             int M, int N, int K, int ldC, float alpha,
             long sA, long sB, long sC,
             long co0, long co1, long co2,
             int mbShift, int ldTv, long sTv)
{
  __shared__ __align__(16) bf16_t smem[4 * 128 * 32];  // 32 KB
  bf16_t* As0 = smem;
  bf16_t* Bs0 = smem + 4096;
  bf16_t* As1 = smem + 8192;
  bf16_t* Bs1 = smem + 12288;

  const int bz = blockIdx.z;
  A  += bz * sA;
  Bt += bz * sB;

  int bx = blockIdx.x, by = blockIdx.y;
  {
    const int gx = gridDim.x, gy = gridDim.y;
    const int nb = gx * gy;
    if (((nb & 7) == 0) && ((gx & 3) == 0) && ((gy & 7) == 0)) {
      const int id   = bx + gx * by;
      const int xcd  = id & 7;
      const int o    = id >> 3;
      const int rows = gy >> 3;
      const int pw   = rows << 2;
      const int p    = o / pw;
      const int r    = o - p * pw;
      by = xcd * rows + (r >> 2);
      bx = (p << 2) + (r & 3);
    }
  }

  const int gn0 = bx * 128;
  const int m0  = by * 128;
  const int tid  = threadIdx.x;
  const int lane = tid & 63;
  const int wave = tid >> 6;
  const int wm   = (wave >> 1) * 64;
  const int wn   = (wave & 1) * 64;
  const int lm   = lane & 15;
  const int quad = lane >> 4;

  int n0 = gn0;
  int which = 0;
  bf16_t* Cb = (bf16_t*)Cv;
  float*  Cf = (float*)Cv;
  const float* bias = b0;
  if (SPLIT3) {
    which = gn0 >> 10;
    n0 = gn0 & 1023;
    Cb += (which == 0) ? co0 : (which == 1) ? co1 : co2;
    bias = (which == 0) ? b0 : (which == 1) ? b1 : b2;
  }

  const int srow   = lane >> 2;
  const int schunk = (lane & 3) * 8;
  const int gchunk = ((lane & 3) ^ ((srow >> 1) & 3)) * 8;
  const int fswz   = ((lm >> 1) & 3) * 8;

  floatx4 acc[4][4];
#pragma unroll
  for (int i = 0; i < 4; ++i)
#pragma unroll
    for (int j = 0; j < 4; ++j)
      acc[i][j] = (floatx4)(0.f);

  for (int kk = 0; kk < K; kk += 64) {
    __syncthreads();
#pragma unroll
    for (int t = 0; t < 2; ++t) {
      const int r = wave * 32 + t * 16 + srow;
      const long ar = (long)(m0  + r) * K + kk + gchunk;
      const long br = (long)(gn0 + r) * K + kk + gchunk;
      gl2lds16(A  + ar,      &As0[r * 32 + schunk]);
      gl2lds16(A  + ar + 32, &As1[r * 32 + schunk]);
      gl2lds16(Bt + br,      &Bs0[r * 32 + schunk]);
      gl2lds16(Bt + br + 32, &Bs1[r * 32 + schunk]);
    }
    __syncthreads();

    {
      bf16x8 af[4], bfr[4];
#pragma unroll
      for (int i = 0; i < 4; ++i)
        af[i] = *(const bf16x8*)&As0[(wm + i * 16 + lm) * 32 + ((quad * 8) ^ fswz)];
#pragma unroll
      for (int j = 0; j < 4; ++j)
        bfr[j] = *(const bf16x8*)&Bs0[(wn + j * 16 + lm) * 32 + ((quad * 8) ^ fswz)];
#pragma unroll
      for (int i = 0; i < 4; ++i)
#pragma unroll
        for (int j = 0; j < 4; ++j)
          acc[i][j] = __builtin_amdgcn_mfma_f32_16x16x32_bf16(af[i], bfr[j],
                                                              acc[i][j], 0, 0, 0);
    }
    {
      bf16x8 af[4], bfr[4];
#pragma unroll
      for (int i = 0; i < 4; ++i)
        af[i] = *(const bf16x8*)&As1[(wm + i * 16 + lm) * 32 + ((quad * 8) ^ fswz)];
#pragma unroll
      for (int j = 0; j < 4; ++j)
        bfr[j] = *(const bf16x8*)&Bs1[(wn + j * 16 + lm) * 32 + ((quad * 8) ^ fswz)];
#pragma unroll
      for (int i = 0; i < 4; ++i)
#pragma unroll
        for (int j = 0; j < 4; ++j)
          acc[i][j] = __builtin_amdgcn_mfma_f32_16x16x32_bf16(af[i], bfr[j],
                                                              acc[i][j], 0, 0, 0);
    }
  }

  if (SPLIT3 && which == 2) {
    __syncthreads();
    bf16_t* myT = smem + wave * (16 * 68);
    const int b  = m0 >> mbShift;
    const int s0 = m0 & ((1 << mbShift) - 1);
    const int r8 = lane >> 3;
    const int c8 = lane & 7;
#pragma unroll
    for (int j = 0; j < 4; ++j) {
      const float bv = HAS_BIAS ? bias[n0 + wn + j * 16 + lm] : 0.f;
#pragma unroll
      for (int i = 0; i < 4; ++i)
#pragma unroll
        for (int r = 0; r < 4; ++r)
          myT[lm * 68 + i * 16 + quad * 4 + r] = (bf16_t)(acc[i][j][r] + bv);
#pragma unroll
      for (int t = 0; t < 2; ++t) {
        const int nr = t * 8 + r8;
        const bf16x8 vv = *(const bf16x8*)&myT[nr * 68 + c8 * 8];
        *(bf16x8*)&Cb[(long)b * sTv + (long)(n0 + wn + j * 16 + nr) * ldTv
                      + s0 + wm + c8 * 8] = vv;
      }
    }
  } else if (OUT_BF16) {
    __syncthreads();
    bf16_t* myEp = smem + wave * (16 * 68);
    const int r8 = lane >> 3;
    const int c8 = lane & 7;
    float cs[4] = {0.f, 0.f, 0.f, 0.f};
#pragma unroll
    for (int i = 0; i < 4; ++i) {
#pragma unroll
      for (int j = 0; j < 4; ++j) {
        const float bv = HAS_BIAS ? bias[n0 + wn + j * 16 + lm] : 0.f;
#pragma unroll
        for (int r = 0; r < 4; ++r) {
          float v = alpha * acc[i][j][r];
          if (EXP_COLSUM) { v = __expf(v); cs[j] += v; }
          v += bv;
          myEp[(quad * 4 + r) * 68 + j * 16 + lm] = (bf16_t)v;
        }
      }
#pragma unroll
      for (int t = 0; t < 2; ++t) {
        const int row = t * 8 + r8;
        const bf16x8 vv = *(const bf16x8*)&myEp[row * 68 + c8 * 8];
        *(bf16x8*)&Cb[bz * sC + (long)(m0 + wm + i * 16 + row) * ldC
                      + n0 + wn + c8 * 8] = vv;
      }
    }
    if (EXP_COLSUM) {
#pragma unroll
      for (int j = 0; j < 4; ++j) {
        float v = cs[j];
        v += __shfl_xor(v, 16);
        v += __shfl_xor(v, 32);
        if (quad == 0)
          atomicAdd(&L[bz * N + gn0 + wn + j * 16 + lm], v);
      }
    }
  } else {
#pragma unroll
    for (int j = 0; j < 4; ++j) {
      const int cn = n0 + wn + j * 16 + lm;
      const float bv = HAS_BIAS ? bias[n0 + wn + j * 16 + lm] : 0.f;
#pragma unroll
      for (int i = 0; i < 4; ++i) {
        const int rbase = m0 + wm + i * 16 + quad * 4;
#pragma unroll
        for (int r = 0; r < 4; ++r)
          Cf[bz * sC + (long)(rbase + r) * ldC + cn] = alpha * acc[i][j][r] + bv;
      }
    }
  }
}

// ---------------------------------------------------------------------------
__global__ __launch_bounds__(256)
void prep(const float* __restrict__ x, bf16_t* __restrict__ Xb,
          const float* __restrict__ w0, const float* __restrict__ w1,
          const float* __restrict__ w2, const float* __restrict__ w3,
          bf16_t* __restrict__ outQKV, bf16_t* __restrict__ outO)
{
  __shared__ float tile[32][33];
  const int id = blockIdx.x;
  if (id < 8192) {
    const long i = ((long)id * 256 + threadIdx.x) * 4;
    const float4 v = *(const float4*)(x + i);
    struct alignas(8) B4 { bf16_t a, b, c, d; };
    B4 o; o.a = (bf16_t)v.x; o.b = (bf16_t)v.y; o.c = (bf16_t)v.z; o.d = (bf16_t)v.w;
    *(B4*)(Xb + i) = o;
  } else {
    const int t = id - 8192;
    const int z = t >> 10;
    const int bx = t & 31, by = (t >> 5) & 31;
    const float* in = (z == 0) ? w0 : (z == 1) ? w1 : (z == 2) ? w2 : w3;
    bf16_t* out = (z < 3) ? outQKV + (long)z * 1024 * 1024 : outO;
    const int c0 = bx * 32, r0 = by * 32;
    const int tx = threadIdx.x & 31;
    const int ty = threadIdx.x >> 5;
#pragma unroll
    for (int i = 0; i < 32; i += 8)
      tile[ty + i][tx] = in[(long)(r0 + ty + i) * 1024 + (c0 + tx)];
    __syncthreads();
#pragma unroll
    for (int i = 0; i < 32; i += 8)
      out[(long)(c0 + ty + i) * 1024 + (r0 + tx)] = (bf16_t)tile[tx][ty + i];
  }
}

// Vt[b][d][s] *= 1/L[b][s]
__global__ __launch_bounds__(256)
void scale_vt(bf16_t* __restrict__ Vt, const float* __restrict__ L, int S)
{
  const long base = ((long)blockIdx.x * blockDim.x + threadIdx.x) * 8;
  const int b  = (int)(base >> 21);
  const int s0 = (int)(base & (long)(S - 1));
  const float* Lb = L + b * S + s0;
  bf16x8 v = *(const bf16x8*)(Vt + base);
#pragma unroll
  for (int j = 0; j < 8; ++j)
    v[j] = (bf16_t)((float)v[j] / Lb[j]);
  *(bf16x8*)(Vt + base) = v;
}

// ---------------------------------------------------------------------------
extern "C" void kernel_launch(void* const* d_in, const int* in_sizes, int n_in,
                              void* d_out, int out_size, void* d_ws, size_t ws_size,
                              hipStream_t stream)
{
  const int Bz = 4, S = 2048, F = 1024, DK = 1024;
  const int M = Bz * S;

  const float* x  = (const float*)d_in[0];
  const float* Wq = (const float*)d_in[1];
  const float* bq = (const float*)d_in[2];
  const float* Wk = (const float*)d_in[3];
  const float* bk = (const float*)d_in[4];
  const float* Wv = (const float*)d_in[5];
  const float* bv = (const float*)d_in[6];
  const float* Wo = (const float*)d_in[7];
  const float* bo = (const float*)d_in[8];

  char* ws = (char*)d_ws;
  const size_t MB = 1ull << 20;
  bf16_t* Xb   = (bf16_t*)(ws + 0);
  bf16_t* Sc   = (bf16_t*)(ws + 0);
  bf16_t* Q    = (bf16_t*)(ws + 32 * MB);
  bf16_t* Ctx  = (bf16_t*)(ws + 32 * MB);
  bf16_t* Kb   = (bf16_t*)(ws + 48 * MB);
  bf16_t* Vt   = (bf16_t*)(ws + 64 * MB);
  bf16_t* WcatT= (bf16_t*)(ws + 80 * MB);
  float*  L    = (float*)(ws + 80 * MB);
  bf16_t* WoT  = (bf16_t*)(ws + 86 * MB);

  const long coQ = 16 * MB;
  const long coK = 24 * MB;
  const long coV = 32 * MB;

  prep<<<12288, 256, 0, stream>>>(x, Xb, Wq, Wk, Wv, Wo, WcatT, WoT);

  // merged Q/K/V projection (256^2 DS-balanced 8-phase); V stored transposed
  gemm256<1, 0, 1><<<dim3(3 * DK / 256, M / 256, 1), 512, 0, stream>>>(
      Xb, WcatT, (void*)ws, bq, bk, bv, nullptr, M, 3 * DK, F, DK, 1.f,
      0, 0, 0, coQ, coK, coV, 11, S, (long)DK * S);

  // P = exp(Q.K/sqrt(dk)); column sums -> L
  hipMemsetAsync(L, 0, (size_t)Bz * S * sizeof(float), stream);
  gemm256<0, 1, 0><<<dim3(S / 256, S / 256, Bz), 512, 0, stream>>>(
      Q, Kb, Sc, nullptr, nullptr, nullptr, L, S, S, DK, S, 0.03125f,
      (long)S * DK, (long)S * DK, (long)S * S, 0, 0, 0, 0, 0, 0);

  scale_vt<<<((long)Bz * DK * S / 8) / 256, 256, 0, stream>>>(Vt, L, S);

  // ctx = P @ (V/L)
  gemm_nt<1, 0, 0, 0><<<dim3(DK / 128, S / 128, Bz), 256, 0, stream>>>(
      Sc, Vt, Ctx, nullptr, nullptr, nullptr, nullptr, S, DK, S, DK, 1.f,
      (long)S * S, (long)S * DK, (long)S * DK, 0, 0, 0, 0, 0, 0);

  // out = ctx @ Wo + bo (fp32)
  gemm_nt<0, 1, 0, 0><<<dim3(F / 128, M / 128, 1), 256, 0, stream>>>(
      Ctx, WoT, d_out, bo, nullptr, nullptr, nullptr, M, F, DK, F, 1.f,
      0, 0, 0, 0, 0, 0, 0, 0, 0);
}